// Round 1
// baseline (208.357 us; speedup 1.0000x reference)
//
#include <hip/hip_runtime.h>

// Problem constants (match reference setup_inputs)
#define N_IN    512
#define NLAYERS 5
#define M_NODES 2048
#define FAN     32
#define B_BATCH 1024
#define E_EDGES (M_NODES * FAN)
#define N_TOTAL (N_IN + NLAYERS * M_NODES)   // 10752

// ---------------------------------------------------------------------------
// Transpose x (B, N_IN) batch-major  ->  vals[node][batch] node-major
// grid (N_IN/32, B/32), block (32, 8)
// ---------------------------------------------------------------------------
__global__ void transpose_in_kernel(const float* __restrict__ x,
                                    float* __restrict__ vals) {
    __shared__ float tile[32][33];
    const int tx = threadIdx.x;   // 0..31
    const int ty = threadIdx.y;   // 0..7
    const int n0 = blockIdx.x * 32;
    const int b0 = blockIdx.y * 32;
#pragma unroll
    for (int i = 0; i < 4; ++i) {
        int b = b0 + ty + i * 8;
        int n = n0 + tx;
        tile[ty + i * 8][tx] = x[(size_t)b * N_IN + n];   // coalesced in n
    }
    __syncthreads();
#pragma unroll
    for (int i = 0; i < 4; ++i) {
        int n = n0 + ty + i * 8;
        int b = b0 + tx;
        vals[(size_t)n * B_BATCH + b] = tile[tx][ty + i * 8];  // coalesced in b
    }
}

// ---------------------------------------------------------------------------
// One DAG layer: for each dst node j (segment of 32 edges), all batch:
//   out[j][b] = relu(bias[j] + sum_k vals[src[j*32+k]][b] * w[j*32+k])
// Block: 256 threads, each thread owns 4 batch elems (float4) -> full B=1024.
// Each block computes NPB destination nodes.
// src/w loads are wave-uniform -> scalar loads; gathers are coalesced rows.
// ---------------------------------------------------------------------------
template <int NPB>
__global__ __launch_bounds__(256) void layer_kernel(
    const float* __restrict__ vals,
    float* __restrict__ outrows,                 // = vals + (N_IN + l*M)*B
    const int* __restrict__ src,                 // this layer's src_idx [E]
    const float* __restrict__ w,                 // this layer's weights [E]
    const float* __restrict__ bias) {            // this layer's biases [M]
    const int t = threadIdx.x;                   // 0..255 -> batch 4t..4t+3
    const int j0 = blockIdx.x * NPB;

#pragma unroll
    for (int jj = 0; jj < NPB; ++jj) {
        const int j = j0 + jj;
        const float bj = bias[j];
        float4 acc0 = make_float4(bj, 0.f, 0.f, 0.f);
        // use 2 accumulators to break the FMA dependence chain
        float4 a0 = make_float4(acc0.x, bj, bj, bj);   // acc0 = bias in all 4
        float4 a1 = make_float4(0.f, 0.f, 0.f, 0.f);
        a0.x = bj;
#pragma unroll
        for (int k = 0; k < FAN; k += 2) {
            const int e = j * FAN + k;
            const int   s0 = src[e];
            const int   s1 = src[e + 1];
            const float w0 = w[e];
            const float w1 = w[e + 1];
            const float4 v0 =
                reinterpret_cast<const float4*>(vals + (size_t)s0 * B_BATCH)[t];
            const float4 v1 =
                reinterpret_cast<const float4*>(vals + (size_t)s1 * B_BATCH)[t];
            a0.x = fmaf(w0, v0.x, a0.x);
            a0.y = fmaf(w0, v0.y, a0.y);
            a0.z = fmaf(w0, v0.z, a0.z);
            a0.w = fmaf(w0, v0.w, a0.w);
            a1.x = fmaf(w1, v1.x, a1.x);
            a1.y = fmaf(w1, v1.y, a1.y);
            a1.z = fmaf(w1, v1.z, a1.z);
            a1.w = fmaf(w1, v1.w, a1.w);
        }
        float4 r;
        r.x = fmaxf(a0.x + a1.x, 0.f);
        r.y = fmaxf(a0.y + a1.y, 0.f);
        r.z = fmaxf(a0.z + a1.z, 0.f);
        r.w = fmaxf(a0.w + a1.w, 0.f);
        reinterpret_cast<float4*>(outrows + (size_t)j * B_BATCH)[t] = r;
    }
}

// ---------------------------------------------------------------------------
// Transpose last layer vals[j][b] (M rows x B cols) -> out[b*M + j]
// grid (M/32, B/32), block (32, 8)
// ---------------------------------------------------------------------------
__global__ void transpose_out_kernel(const float* __restrict__ lastrows,
                                     float* __restrict__ out) {
    __shared__ float tile[32][33];
    const int tx = threadIdx.x;
    const int ty = threadIdx.y;
    const int j0 = blockIdx.x * 32;
    const int b0 = blockIdx.y * 32;
#pragma unroll
    for (int i = 0; i < 4; ++i) {
        int j = j0 + ty + i * 8;
        int b = b0 + tx;
        tile[ty + i * 8][tx] = lastrows[(size_t)j * B_BATCH + b];  // coalesced
    }
    __syncthreads();
#pragma unroll
    for (int i = 0; i < 4; ++i) {
        int b = b0 + ty + i * 8;
        int j = j0 + tx;
        out[(size_t)b * M_NODES + j] = tile[tx][ty + i * 8];       // coalesced
    }
}

extern "C" void kernel_launch(void* const* d_in, const int* in_sizes, int n_in,
                              void* d_out, int out_size, void* d_ws, size_t ws_size,
                              hipStream_t stream) {
    const float* x       = (const float*)d_in[0];   // (B, N_IN)
    const float* weights = (const float*)d_in[1];   // (L, E)
    const float* biases  = (const float*)d_in[2];   // (L, M)
    const int*   src_idx = (const int*)d_in[3];     // (L, E)
    // d_in[4] = dst_idx: structurally repeat(arange(M), FAN) -> segment j = e/FAN
    float* out  = (float*)d_out;                    // (B, M) batch-major
    float* vals = (float*)d_ws;                     // [N_TOTAL][B] node-major, 44 MB

    // 1) inputs -> node-major vals[0:512]
    transpose_in_kernel<<<dim3(N_IN / 32, B_BATCH / 32), dim3(32, 8), 0, stream>>>(
        x, vals);

    // 2) layers (sequential launches = topological sync)
    constexpr int NPB = 2;   // nodes per block -> 1024 blocks/layer (~4/CU)
    for (int l = 0; l < NLAYERS; ++l) {
        float* outrows = vals + (size_t)(N_IN + l * M_NODES) * B_BATCH;
        layer_kernel<NPB><<<M_NODES / NPB, 256, 0, stream>>>(
            vals, outrows,
            src_idx + (size_t)l * E_EDGES,
            weights + (size_t)l * E_EDGES,
            biases  + (size_t)l * M_NODES);
    }

    // 3) last layer rows -> batch-major output
    transpose_out_kernel<<<dim3(M_NODES / 32, B_BATCH / 32), dim3(32, 8), 0, stream>>>(
        vals + (size_t)(N_IN + (NLAYERS - 1) * M_NODES) * B_BATCH, out);
}

// Round 2
// 148.869 us; speedup vs baseline: 1.3996x; 1.3996x over previous
//
#include <hip/hip_runtime.h>

// Problem constants (match reference setup_inputs)
#define N_IN    512
#define NLAYERS 5
#define M_NODES 2048
#define FAN     32
#define B_BATCH 1024
#define E_EDGES (M_NODES * FAN)
#define N_TOTAL (N_IN + NLAYERS * M_NODES)   // 10752

// Batch slicing for XCD-local L2 residency:
// vals layout: [slice][node][SLICE_B]  (8 slices x 128 batch)
// One slice's full working set = 10752 * 512 B = 5.5 MB (prefix <= 4.35 MB at
// the deepest layer) ~ one XCD's 4 MB L2. slice = blockIdx.x & 7 rides the
// round-robin block->XCD dispatch so each slice's gathers stay in one L2.
#define SLICES  8
#define SLICE_B 128        // floats per row per slice = 32 lanes x float4

// ---------------------------------------------------------------------------
// Transpose x (B, N_IN) batch-major -> sliced node-major vals[slice][n][bb]
// grid (N_IN/32, B/32), block (32, 8)
// ---------------------------------------------------------------------------
__global__ void transpose_in_kernel(const float* __restrict__ x,
                                    float* __restrict__ vals) {
    __shared__ float tile[32][33];
    const int tx = threadIdx.x;   // 0..31
    const int ty = threadIdx.y;   // 0..7
    const int n0 = blockIdx.x * 32;
    const int b0 = blockIdx.y * 32;
#pragma unroll
    for (int i = 0; i < 4; ++i) {
        int b = b0 + ty + i * 8;
        int n = n0 + tx;
        tile[ty + i * 8][tx] = x[(size_t)b * N_IN + n];   // coalesced in n
    }
    __syncthreads();
#pragma unroll
    for (int i = 0; i < 4; ++i) {
        int n  = n0 + ty + i * 8;
        int b  = b0 + tx;                 // 32 consecutive b -> same slice
        int sl = b >> 7;
        int bb = b & (SLICE_B - 1);
        vals[((size_t)sl * N_TOTAL + n) * SLICE_B + bb] = tile[tx][ty + i * 8];
    }
}

// ---------------------------------------------------------------------------
// One DAG layer, one batch-slice per block (slice = blockIdx.x & 7):
//   out[j][bb] = relu(bias[j] + sum_k vals[s][src[j*32+k]][bb] * w[j*32+k])
// Block: 256 threads = 8 half-waves; each half-wave owns one node; each lane
// owns 4 batch elems (float4 over SLICE_B=128). NPN nodes per half-wave.
// ---------------------------------------------------------------------------
template <int NPN>
__global__ __launch_bounds__(256) void layer_kernel(
    float* __restrict__ vals,
    const int base,                              // N_IN + l*M (output node base)
    const int* __restrict__ src,                 // this layer's src_idx [E]
    const float* __restrict__ w,                 // this layer's weights [E]
    const float* __restrict__ bias) {            // this layer's biases [M]
    const int slice = blockIdx.x & (SLICES - 1);
    const int group = blockIdx.x >> 3;           // node group within layer
    const int h     = threadIdx.x >> 5;          // half-wave id 0..7
    const int lane  = threadIdx.x & 31;          // batch float4 index

    float* vslice = vals + (size_t)slice * N_TOTAL * SLICE_B;

#pragma unroll
    for (int n = 0; n < NPN; ++n) {
        const int j = group * (8 * NPN) + n * 8 + h;
        const float bj = bias[j];
        float4 a0 = make_float4(bj, bj, bj, bj);
        float4 a1 = make_float4(0.f, 0.f, 0.f, 0.f);
        const int ebase = j * FAN;
#pragma unroll
        for (int k = 0; k < FAN; k += 2) {
            const int   s0 = src[ebase + k];
            const int   s1 = src[ebase + k + 1];
            const float w0 = w[ebase + k];
            const float w1 = w[ebase + k + 1];
            const float4 v0 =
                reinterpret_cast<const float4*>(vslice + (size_t)s0 * SLICE_B)[lane];
            const float4 v1 =
                reinterpret_cast<const float4*>(vslice + (size_t)s1 * SLICE_B)[lane];
            a0.x = fmaf(w0, v0.x, a0.x);
            a0.y = fmaf(w0, v0.y, a0.y);
            a0.z = fmaf(w0, v0.z, a0.z);
            a0.w = fmaf(w0, v0.w, a0.w);
            a1.x = fmaf(w1, v1.x, a1.x);
            a1.y = fmaf(w1, v1.y, a1.y);
            a1.z = fmaf(w1, v1.z, a1.z);
            a1.w = fmaf(w1, v1.w, a1.w);
        }
        float4 r;
        r.x = fmaxf(a0.x + a1.x, 0.f);
        r.y = fmaxf(a0.y + a1.y, 0.f);
        r.z = fmaxf(a0.z + a1.z, 0.f);
        r.w = fmaxf(a0.w + a1.w, 0.f);
        reinterpret_cast<float4*>(vslice + (size_t)(base + j) * SLICE_B)[lane] = r;
    }
}

// ---------------------------------------------------------------------------
// Sliced last-layer rows -> batch-major out[b*M + j]
// grid (M/32, B/32), block (32, 8)
// ---------------------------------------------------------------------------
__global__ void transpose_out_kernel(const float* __restrict__ vals,
                                     float* __restrict__ out) {
    __shared__ float tile[32][33];
    const int tx = threadIdx.x;
    const int ty = threadIdx.y;
    const int j0 = blockIdx.x * 32;
    const int b0 = blockIdx.y * 32;
    const int node0 = N_IN + (NLAYERS - 1) * M_NODES;
#pragma unroll
    for (int i = 0; i < 4; ++i) {
        int j  = j0 + ty + i * 8;
        int b  = b0 + tx;                 // consecutive bb within one slice
        int sl = b >> 7;
        int bb = b & (SLICE_B - 1);
        tile[ty + i * 8][tx] =
            vals[((size_t)sl * N_TOTAL + node0 + j) * SLICE_B + bb];
    }
    __syncthreads();
#pragma unroll
    for (int i = 0; i < 4; ++i) {
        int b = b0 + ty + i * 8;
        int j = j0 + tx;
        out[(size_t)b * M_NODES + j] = tile[tx][ty + i * 8];       // coalesced
    }
}

extern "C" void kernel_launch(void* const* d_in, const int* in_sizes, int n_in,
                              void* d_out, int out_size, void* d_ws, size_t ws_size,
                              hipStream_t stream) {
    const float* x       = (const float*)d_in[0];   // (B, N_IN)
    const float* weights = (const float*)d_in[1];   // (L, E)
    const float* biases  = (const float*)d_in[2];   // (L, M)
    const int*   src_idx = (const int*)d_in[3];     // (L, E)
    // d_in[4] = dst_idx: structurally repeat(arange(M), FAN) -> segment j = e/FAN
    float* out  = (float*)d_out;                    // (B, M) batch-major
    float* vals = (float*)d_ws;                     // [8][N_TOTAL][128], 44 MB

    // 1) inputs -> sliced node-major vals
    transpose_in_kernel<<<dim3(N_IN / 32, B_BATCH / 32), dim3(32, 8), 0, stream>>>(
        x, vals);

    // 2) layers (sequential launches = topological sync)
    constexpr int NPN = 2;   // nodes per half-wave -> 16 nodes/block
    // blocks = SLICES * M/(8*NPN) = 8 * 128 = 1024  (~4 blocks/CU, 16 waves/CU)
    for (int l = 0; l < NLAYERS; ++l) {
        layer_kernel<NPN><<<SLICES * (M_NODES / (8 * NPN)), 256, 0, stream>>>(
            vals, N_IN + l * M_NODES,
            src_idx + (size_t)l * E_EDGES,
            weights + (size_t)l * E_EDGES,
            biases  + (size_t)l * M_NODES);
    }

    // 3) last layer rows -> batch-major output
    transpose_out_kernel<<<dim3(M_NODES / 32, B_BATCH / 32), dim3(32, 8), 0, stream>>>(
        vals, out);
}

// Round 3
// 139.321 us; speedup vs baseline: 1.4955x; 1.0685x over previous
//
#include <hip/hip_runtime.h>

// Problem constants (match reference setup_inputs)
#define N_IN    512
#define NLAYERS 5
#define M_NODES 2048
#define FAN     32
#define B_BATCH 1024
#define E_EDGES (M_NODES * FAN)
#define N_TOTAL (N_IN + NLAYERS * M_NODES)   // 10752

// Batch slicing for XCD-local L2 residency:
// vals layout: [slice][node][SLICE_B]  (8 slices x 128 batch)
// One slice's prefix working set <= 4.35 MB ~ one XCD's 4 MB L2.
// slice = blockIdx.x & 7 rides the round-robin block->XCD dispatch.
#define SLICES  8
#define SLICE_B 128        // floats per row per slice = 32 lanes x float4

// ---------------------------------------------------------------------------
// Transpose x (B, N_IN) batch-major -> sliced node-major vals[slice][n][bb]
// ---------------------------------------------------------------------------
__global__ void transpose_in_kernel(const float* __restrict__ x,
                                    float* __restrict__ vals) {
    __shared__ float tile[32][33];
    const int tx = threadIdx.x;   // 0..31
    const int ty = threadIdx.y;   // 0..7
    const int n0 = blockIdx.x * 32;
    const int b0 = blockIdx.y * 32;
#pragma unroll
    for (int i = 0; i < 4; ++i) {
        int b = b0 + ty + i * 8;
        int n = n0 + tx;
        tile[ty + i * 8][tx] = x[(size_t)b * N_IN + n];   // coalesced in n
    }
    __syncthreads();
#pragma unroll
    for (int i = 0; i < 4; ++i) {
        int n  = n0 + ty + i * 8;
        int b  = b0 + tx;                 // 32 consecutive b -> same slice
        int sl = b >> 7;
        int bb = b & (SLICE_B - 1);
        vals[((size_t)sl * N_TOTAL + n) * SLICE_B + bb] = tile[tx][ty + i * 8];
    }
}

// ---------------------------------------------------------------------------
// One DAG layer, one batch-slice per block (slice = blockIdx.x & 7):
//   out[j][bb] = relu(bias[j] + sum_k vals[s][src[j*32+k]][bb] * w[j*32+k])
// Block: 256 threads = 8 half-waves; each half-wave owns ONE node; each lane
// owns 4 batch elems (float4 over SLICE_B=128). 2048 blocks -> 32 waves/CU.
// Edges (src,w) for the block's 8 nodes are staged in LDS with one coalesced
// load each, so the gather stream owns the VMEM pipe and index reads are
// near-free LDS broadcasts (same address within a half-wave).
// ---------------------------------------------------------------------------
__global__ __launch_bounds__(256) void layer_kernel(
    float* __restrict__ vals,
    const int base,                              // N_IN + l*M (output node base)
    const int* __restrict__ src,                 // this layer's src_idx [E]
    const float* __restrict__ w,                 // this layer's weights [E]
    const float* __restrict__ bias) {            // this layer's biases [M]
    __shared__ int   s_src[256];
    __shared__ float s_w[256];

    const int slice = blockIdx.x & (SLICES - 1);
    const int group = blockIdx.x >> 3;           // node group (8 nodes) in layer
    const int t     = threadIdx.x;
    const int h     = t >> 5;                    // half-wave id 0..7
    const int lane  = t & 31;                    // batch float4 index

    // stage this block's 256 edges (coalesced, one dword each)
    const int eblk = group * 256;
    s_src[t] = src[eblk + t];
    s_w[t]   = w[eblk + t];
    __syncthreads();

    float* vslice = vals + (size_t)slice * N_TOTAL * SLICE_B;

    const int j = group * 8 + h;
    const float bj = bias[j];
    float4 a0 = make_float4(bj, bj, bj, bj);
    float4 a1 = make_float4(0.f, 0.f, 0.f, 0.f);
    float4 a2 = make_float4(0.f, 0.f, 0.f, 0.f);
    float4 a3 = make_float4(0.f, 0.f, 0.f, 0.f);

    const int kbase = h * 32;
#pragma unroll
    for (int k = 0; k < FAN; k += 4) {
        const int   s0 = s_src[kbase + k];
        const int   s1 = s_src[kbase + k + 1];
        const int   s2 = s_src[kbase + k + 2];
        const int   s3 = s_src[kbase + k + 3];
        const float w0 = s_w[kbase + k];
        const float w1 = s_w[kbase + k + 1];
        const float w2 = s_w[kbase + k + 2];
        const float w3 = s_w[kbase + k + 3];
        const float4 v0 =
            reinterpret_cast<const float4*>(vslice + (size_t)s0 * SLICE_B)[lane];
        const float4 v1 =
            reinterpret_cast<const float4*>(vslice + (size_t)s1 * SLICE_B)[lane];
        const float4 v2 =
            reinterpret_cast<const float4*>(vslice + (size_t)s2 * SLICE_B)[lane];
        const float4 v3 =
            reinterpret_cast<const float4*>(vslice + (size_t)s3 * SLICE_B)[lane];
        a0.x = fmaf(w0, v0.x, a0.x);
        a0.y = fmaf(w0, v0.y, a0.y);
        a0.z = fmaf(w0, v0.z, a0.z);
        a0.w = fmaf(w0, v0.w, a0.w);
        a1.x = fmaf(w1, v1.x, a1.x);
        a1.y = fmaf(w1, v1.y, a1.y);
        a1.z = fmaf(w1, v1.z, a1.z);
        a1.w = fmaf(w1, v1.w, a1.w);
        a2.x = fmaf(w2, v2.x, a2.x);
        a2.y = fmaf(w2, v2.y, a2.y);
        a2.z = fmaf(w2, v2.z, a2.z);
        a2.w = fmaf(w2, v2.w, a2.w);
        a3.x = fmaf(w3, v3.x, a3.x);
        a3.y = fmaf(w3, v3.y, a3.y);
        a3.z = fmaf(w3, v3.z, a3.z);
        a3.w = fmaf(w3, v3.w, a3.w);
    }
    float4 r;
    r.x = fmaxf((a0.x + a1.x) + (a2.x + a3.x), 0.f);
    r.y = fmaxf((a0.y + a1.y) + (a2.y + a3.y), 0.f);
    r.z = fmaxf((a0.z + a1.z) + (a2.z + a3.z), 0.f);
    r.w = fmaxf((a0.w + a1.w) + (a2.w + a3.w), 0.f);
    reinterpret_cast<float4*>(vslice + (size_t)(base + j) * SLICE_B)[lane] = r;
}

// ---------------------------------------------------------------------------
// Sliced last-layer rows -> batch-major out[b*M + j]
// ---------------------------------------------------------------------------
__global__ void transpose_out_kernel(const float* __restrict__ vals,
                                     float* __restrict__ out) {
    __shared__ float tile[32][33];
    const int tx = threadIdx.x;
    const int ty = threadIdx.y;
    const int j0 = blockIdx.x * 32;
    const int b0 = blockIdx.y * 32;
    const int node0 = N_IN + (NLAYERS - 1) * M_NODES;
#pragma unroll
    for (int i = 0; i < 4; ++i) {
        int j  = j0 + ty + i * 8;
        int b  = b0 + tx;                 // consecutive bb within one slice
        int sl = b >> 7;
        int bb = b & (SLICE_B - 1);
        tile[ty + i * 8][tx] =
            vals[((size_t)sl * N_TOTAL + node0 + j) * SLICE_B + bb];
    }
    __syncthreads();
#pragma unroll
    for (int i = 0; i < 4; ++i) {
        int b = b0 + ty + i * 8;
        int j = j0 + tx;
        out[(size_t)b * M_NODES + j] = tile[tx][ty + i * 8];       // coalesced
    }
}

extern "C" void kernel_launch(void* const* d_in, const int* in_sizes, int n_in,
                              void* d_out, int out_size, void* d_ws, size_t ws_size,
                              hipStream_t stream) {
    const float* x       = (const float*)d_in[0];   // (B, N_IN)
    const float* weights = (const float*)d_in[1];   // (L, E)
    const float* biases  = (const float*)d_in[2];   // (L, M)
    const int*   src_idx = (const int*)d_in[3];     // (L, E)
    // d_in[4] = dst_idx: structurally repeat(arange(M), FAN) -> segment j = e/FAN
    float* out  = (float*)d_out;                    // (B, M) batch-major
    float* vals = (float*)d_ws;                     // [8][N_TOTAL][128], 44 MB

    // 1) inputs -> sliced node-major vals
    transpose_in_kernel<<<dim3(N_IN / 32, B_BATCH / 32), dim3(32, 8), 0, stream>>>(
        x, vals);

    // 2) layers (sequential launches = topological sync)
    // blocks = SLICES * M/8 = 2048 -> 8 blocks/CU, 32 waves/CU (max occupancy)
    for (int l = 0; l < NLAYERS; ++l) {
        layer_kernel<<<SLICES * (M_NODES / 8), 256, 0, stream>>>(
            vals, N_IN + l * M_NODES,
            src_idx + (size_t)l * E_EDGES,
            weights + (size_t)l * E_EDGES,
            biases  + (size_t)l * M_NODES);
    }

    // 3) last layer rows -> batch-major output
    transpose_out_kernel<<<dim3(M_NODES / 32, B_BATCH / 32), dim3(32, 8), 0, stream>>>(
        vals, out);
}